// Round 1
// baseline (1328.512 us; speedup 1.0000x reference)
//
#include <hip/hip_runtime.h>

// Problem constants
#define NB   16384      // number of graphs (B)
#define NN   32         // agents per graph (N)
#define DINC 275        // input feature dim
#define HH   64         // hidden dim
#define AA   14         // action dim
#define Q_ELEMS   ((size_t)NB * NN * AA)        // 7,340,032
#define HID_ELEMS ((size_t)NB * NN * HH)        // 33,554,432

// One attention layer operating on the 32x64 tile in sH (padded stride 65).
// sQ/sK/sV are scratch (stride 65), sS is the att matrix (stride 33).
__device__ __forceinline__ void att_layer(
    const float* __restrict__ Wv, const float* __restrict__ bv,
    const float* __restrict__ Wk, const float* __restrict__ bk,
    const float* __restrict__ Wq, const float* __restrict__ bq,
    float* sH, float* sQ, float* sK, float* sV,
    const float* sAdj, float* sS, int tid)
{
    const int j = tid & 63;        // output column (0..63)
    const int g = tid >> 6;        // wave id (0..3)
    const int r0 = g * 8;          // this wave's 8 rows

    // ---- Q,K,V = relu(h @ W + b), three 32x64x64 GEMMs fused ----
    float aq[8], ak[8], av[8];
#pragma unroll
    for (int i = 0; i < 8; ++i) { aq[i] = 0.f; ak[i] = 0.f; av[i] = 0.f; }
#pragma unroll 4
    for (int kk = 0; kk < HH; ++kk) {
        float wq = Wq[kk * HH + j];     // coalesced, L2-resident
        float wk = Wk[kk * HH + j];
        float wv = Wv[kk * HH + j];
#pragma unroll
        for (int i = 0; i < 8; ++i) {
            float h = sH[(r0 + i) * 65 + kk];   // wave-broadcast LDS read
            aq[i] = fmaf(h, wq, aq[i]);
            ak[i] = fmaf(h, wk, ak[i]);
            av[i] = fmaf(h, wv, av[i]);
        }
    }
    {
        float bq_ = bq[j], bk_ = bk[j], bv_ = bv[j];
#pragma unroll
        for (int i = 0; i < 8; ++i) {
            sQ[(r0 + i) * 65 + j] = fmaxf(aq[i] + bq_, 0.f);
            sK[(r0 + i) * 65 + j] = fmaxf(ak[i] + bk_, 0.f);
            sV[(r0 + i) * 65 + j] = fmaxf(av[i] + bv_, 0.f);
        }
    }
    __syncthreads();

    // ---- scores[n][m] = q[n].k[m]; mask; softmax over m (wave-parallel) ----
    const int m  = tid & 31;       // key index
    const int ng = tid >> 5;       // row group (0..7), rows n = ng*4 + i
    float sc[4];
#pragma unroll
    for (int i = 0; i < 4; ++i) sc[i] = 0.f;
#pragma unroll 4
    for (int h = 0; h < HH; ++h) {
        float kv = sK[m * 65 + h];                 // stride-65: conflict-free
#pragma unroll
        for (int i = 0; i < 4; ++i)
            sc[i] = fmaf(sQ[(ng * 4 + i) * 65 + h], kv, sc[i]);  // broadcast
    }
#pragma unroll
    for (int i = 0; i < 4; ++i) {
        int n = ng * 4 + i;
        float mk = sAdj[n * 32 + m];
        float v  = sc[i] * mk - 9e15f * (1.f - mk);
        float mx = v;
#pragma unroll
        for (int off = 16; off; off >>= 1)
            mx = fmaxf(mx, __shfl_xor(mx, off, 32));   // 32-lane segment
        float e = __expf(v - mx);
        float s = e;
#pragma unroll
        for (int off = 16; off; off >>= 1)
            s += __shfl_xor(s, off, 32);
        sS[n * 33 + m] = e / s;
    }
    __syncthreads();

    // ---- h_new[n][j] = sum_m att[n][m] * v[m][j] ----
    float hn[8];
#pragma unroll
    for (int i = 0; i < 8; ++i) hn[i] = 0.f;
#pragma unroll 4
    for (int mm = 0; mm < NN; ++mm) {
        float vv = sV[mm * 65 + j];                // conflict-free
#pragma unroll
        for (int i = 0; i < 8; ++i)
            hn[i] = fmaf(sS[(r0 + i) * 33 + mm], vv, hn[i]);   // broadcast
    }
    // sH reads (QKV phase) are long done; safe to overwrite after PV compute.
#pragma unroll
    for (int i = 0; i < 8; ++i) sH[(r0 + i) * 65 + j] = hn[i];
    __syncthreads();
}

__global__ __launch_bounds__(256) void dgn_fused(
    const float* __restrict__ X,        // [B*N, 275]
    const float* __restrict__ adj,      // [B, 32, 32]
    const float* __restrict__ W_enc, const float* __restrict__ b_enc,
    const float* __restrict__ Wv1, const float* __restrict__ bv1,
    const float* __restrict__ Wk1, const float* __restrict__ bk1,
    const float* __restrict__ Wq1, const float* __restrict__ bq1,
    const float* __restrict__ Wv2, const float* __restrict__ bv2,
    const float* __restrict__ Wk2, const float* __restrict__ bk2,
    const float* __restrict__ Wq2, const float* __restrict__ bq2,
    const float* __restrict__ Wqn, const float* __restrict__ bqn,
    float* __restrict__ Out)            // [B, 32, 14]
{
    // LDS: X tile (8800 f) union-aliased with Q/K/V (3*2080 f = 6240 f)
    __shared__ float sBig[8800];
    __shared__ float sH[NN * 65];
    __shared__ float sAdj[NN * NN];
    __shared__ float sS[NN * 33];
    float* sX = sBig;
    float* sQ = sBig;
    float* sK = sBig + 2080;
    float* sV = sBig + 4160;

    const int b   = blockIdx.x;
    const int tid = threadIdx.x;
    const int j   = tid & 63;
    const int g   = tid >> 6;
    const int r0  = g * 8;

    // ---- stage X tile (32x275 = 2200 float4, contiguous) + adj ----
    {
        const float4* Xg = (const float4*)(X + (size_t)b * NN * DINC);
        float4* sX4 = (float4*)sX;
        for (int i = tid; i < 2200; i += 256) sX4[i] = Xg[i];
        const float4* Ag = (const float4*)(adj + (size_t)b * NN * NN);
        ((float4*)sAdj)[tid] = Ag[tid];
    }
    __syncthreads();

    // ---- encoder: h1 = relu(X @ W_enc + b_enc), 32x275x64 ----
    {
        float acc[8];
#pragma unroll
        for (int i = 0; i < 8; ++i) acc[i] = 0.f;
#pragma unroll 5
        for (int k = 0; k < DINC; ++k) {
            float w = W_enc[k * HH + j];            // coalesced, L2-resident
#pragma unroll
            for (int i = 0; i < 8; ++i)
                acc[i] = fmaf(sX[(r0 + i) * DINC + k], w, acc[i]); // broadcast
        }
        float be = b_enc[j];
#pragma unroll
        for (int i = 0; i < 8; ++i)
            sH[(r0 + i) * 65 + j] = fmaxf(acc[i] + be, 0.f);
    }
    __syncthreads();   // sX dead from here; sBig reused as Q/K/V

    att_layer(Wv1, bv1, Wk1, bk1, Wq1, bq1, sH, sQ, sK, sV, sAdj, sS, tid);
    att_layer(Wv2, bv2, Wk2, bk2, Wq2, bq2, sH, sQ, sK, sV, sAdj, sS, tid);

    // ---- head: q = h3 @ Wqn + bqn  (32x14 outputs) ----
    for (int idx = tid; idx < NN * AA; idx += 256) {
        int n = idx / AA;
        int a = idx - n * AA;
        float accq = bqn[a];
#pragma unroll 8
        for (int h = 0; h < HH; ++h)
            accq = fmaf(sH[n * 65 + h], Wqn[h * AA + a], accq);
        Out[((size_t)b * NN + n) * AA + a] = accq;
    }
}

__global__ void copy_hidden(const float4* __restrict__ src,
                            float4* __restrict__ dst, int n4)
{
    int i = blockIdx.x * blockDim.x + threadIdx.x;
    int stride = gridDim.x * blockDim.x;
    for (; i < n4; i += stride) dst[i] = src[i];
}

extern "C" void kernel_launch(void* const* d_in, const int* in_sizes, int n_in,
                              void* d_out, int out_size, void* d_ws, size_t ws_size,
                              hipStream_t stream)
{
    const float* X    = (const float*)d_in[0];
    const float* hid  = (const float*)d_in[1];
    const float* adj  = (const float*)d_in[2];
    const float* W_enc = (const float*)d_in[3];
    const float* b_enc = (const float*)d_in[4];
    const float* Wv1 = (const float*)d_in[5];
    const float* bv1 = (const float*)d_in[6];
    const float* Wk1 = (const float*)d_in[7];
    const float* bk1 = (const float*)d_in[8];
    const float* Wq1 = (const float*)d_in[9];
    const float* bq1 = (const float*)d_in[10];
    const float* Wv2 = (const float*)d_in[11];
    const float* bv2 = (const float*)d_in[12];
    const float* Wk2 = (const float*)d_in[13];
    const float* bk2 = (const float*)d_in[14];
    const float* Wq2 = (const float*)d_in[15];
    const float* bq2 = (const float*)d_in[16];
    const float* Wqn = (const float*)d_in[17];
    const float* bqn = (const float*)d_in[18];
    float* out = (float*)d_out;

    dgn_fused<<<NB, 256, 0, stream>>>(X, adj, W_enc, b_enc,
                                      Wv1, bv1, Wk1, bk1, Wq1, bq1,
                                      Wv2, bv2, Wk2, bk2, Wq2, bq2,
                                      Wqn, bqn, out);

    // hidden_state pass-through into the second output region
    copy_hidden<<<2048, 256, 0, stream>>>((const float4*)hid,
                                          (float4*)(out + Q_ELEMS),
                                          (int)(HID_ELEMS / 4));
}

// Round 2
// 520.709 us; speedup vs baseline: 2.5514x; 2.5514x over previous
//
#include <hip/hip_runtime.h>

// ---------------- problem constants ----------------
#define NB 16384
#define NN 32
#define DK 275
#define HH 64
#define AA 14
#define Q_ELEMS   ((size_t)NB * NN * AA)
#define HID_ELEMS ((size_t)NB * NN * HH)

typedef unsigned short u16;
typedef unsigned int   u32;
typedef __attribute__((ext_vector_type(8))) short s8v;   // 8 bf16 (4 VGPR)
typedef __attribute__((ext_vector_type(4))) float f4v;   // MFMA acc

#define MFMA(a,b,c) __builtin_amdgcn_mfma_f32_16x16x32_bf16((a),(b),(c),0,0,0)

// bf16 split helpers (RNE)
__device__ __forceinline__ u16 bf_hi(float x){
    union{float f; u32 u;} v; v.f = x;
    u32 r = v.u + 0x7fffu + ((v.u >> 16) & 1u);
    return (u16)(r >> 16);
}
__device__ __forceinline__ float bf_f(u16 h){
    union{u32 u; float f;} v; v.u = ((u32)h) << 16; return v.f;
}

// ---------------- ws (prepacked weight fragments) layout ----------------
// block of 1KB = 64 lanes x 16B; lane l holds 8 bf16 = W[32*s+8*(l>>4)+e][16*mt+(l&15)]
// region offsets (bytes):
#define WSE_OFF 0
#define WSE_SZ  (2*4*9*1024)            // W_enc: part(2) x mt(4) x step(9)   = 73728
#define WSL_SZ  (2*4*2*1024)            // each QKV mat: part x mt(4) x step(2) = 16384
#define WSQN_OFF (WSE_SZ + 6*WSL_SZ)    // 172032
#define WS_TOTAL (WSQN_OFF + 2*1*2*1024) // 176128

__global__ void prepack_w(const float* __restrict__ We,
                          const float* __restrict__ Wv1, const float* __restrict__ Wk1, const float* __restrict__ Wq1,
                          const float* __restrict__ Wv2, const float* __restrict__ Wk2, const float* __restrict__ Wq2,
                          const float* __restrict__ Wqn, char* __restrict__ ws)
{
    int gid  = blockIdx.x * 256 + threadIdx.x;     // 172 slots x 64 lanes
    int slot = gid >> 6, lane = gid & 63;
    const float* W; int K, OUT, STEPS, MT; size_t base; int rem;
    if (slot < 72) { W = We; K = DK; OUT = 64; STEPS = 9; MT = 4; base = WSE_OFF; rem = slot; }
    else if (slot < 168) {
        int q = slot - 72; int mat = q >> 4; rem = q & 15;
        W = mat==0?Wv1 : mat==1?Wk1 : mat==2?Wq1 : mat==3?Wv2 : mat==4?Wk2 : Wq2;
        K = 64; OUT = 64; STEPS = 2; MT = 4; base = WSE_SZ + (size_t)mat * WSL_SZ;
    } else { W = Wqn; K = 64; OUT = AA; STEPS = 2; MT = 1; base = WSQN_OFF; rem = slot - 168; }
    // rem = (part*MT + mt)*STEPS + s  -- matches main-kernel addressing
    int o  = 16 * (((rem / STEPS) % MT)) + (lane & 15);
    int part = (rem / STEPS) / MT;
    int s  = rem % STEPS;
    int kb = 32 * s + 8 * (lane >> 4);
    u16 h[8];
#pragma unroll
    for (int e = 0; e < 8; ++e) {
        int k = kb + e;
        float x = (k < K && o < OUT) ? W[(size_t)k * OUT + o] : 0.f;
        u16 hi = bf_hi(x);
        h[e] = (part == 0) ? hi : bf_hi(x - bf_f(hi));
    }
    uint4 d;
    d.x = (u32)h[0] | ((u32)h[1] << 16);
    d.y = (u32)h[2] | ((u32)h[3] << 16);
    d.z = (u32)h[4] | ((u32)h[5] << 16);
    d.w = (u32)h[6] | ((u32)h[7] << 16);
    *(uint4*)(ws + base + (size_t)rem * 1024 + (size_t)lane * 16) = d;
}

// ---------------- LDS layout (bytes) ----------------
// planes: row-stride 144B (72 bf16) for h/Q/K, 80B (40 bf16) for Vt/P  -> 16B aligned, ~2-way banks
#define SM_X    0            // 32x275 f32 staging = 35200 (dead after encoder)
#define SM_QHI  0            // overlay of X region:
#define SM_QLO  4608
#define SM_KHI  9216
#define SM_KLO  13824
#define SM_VTHI 18432        // Vt: [feat 64][agent pad 40] = 5120
#define SM_VTLO 23552
#define SM_PHI  28672        // P:  [q 32][k pad 40] = 2560
#define SM_PLO  31232        // ..33792  (< 35200, fits in X overlay)
#define SM_HHI  35200        // h: [agent 32][feat pad 72] = 4608
#define SM_HLO  39808
#define SM_SS   44416        // scores f32 32x33 = 4224
#define SM_ADJ  48640        // 4096
#define SM_TOT  52736

__device__ __forceinline__ f4v relu4(f4v v){
    f4v r; r[0]=fmaxf(v[0],0.f); r[1]=fmaxf(v[1],0.f);
    r[2]=fmaxf(v[2],0.f); r[3]=fmaxf(v[3],0.f); return r;
}
// write 4 k-consecutive bf16 hi/lo (one b64 store each)
__device__ __forceinline__ void write_hl4(char* hp, char* lp, f4v v){
    u16 h0=bf_hi(v[0]), h1=bf_hi(v[1]), h2=bf_hi(v[2]), h3=bf_hi(v[3]);
    uint2 hw; hw.x = (u32)h0 | ((u32)h1<<16); hw.y = (u32)h2 | ((u32)h3<<16);
    u16 l0=bf_hi(v[0]-bf_f(h0)), l1=bf_hi(v[1]-bf_f(h1));
    u16 l2=bf_hi(v[2]-bf_f(h2)), l3=bf_hi(v[3]-bf_f(h3));
    uint2 lw; lw.x = (u32)l0 | ((u32)l1<<16); lw.y = (u32)l2 | ((u32)l3<<16);
    *(uint2*)hp = hw; *(uint2*)lp = lw;
}

__global__ __launch_bounds__(256) void dgn_mfma(
    const float* __restrict__ X, const float* __restrict__ adj,
    const char*  __restrict__ ws,
    const float* __restrict__ b_enc,
    const float* __restrict__ bv1, const float* __restrict__ bk1, const float* __restrict__ bq1,
    const float* __restrict__ bv2, const float* __restrict__ bk2, const float* __restrict__ bq2,
    const float* __restrict__ bqn,
    float* __restrict__ Out)
{
    __shared__ __align__(16) char sm[SM_TOT];
    const int b = blockIdx.x, tid = threadIdx.x;
    const int w = tid >> 6, l = tid & 63, lr = l & 15, lg = l >> 4;
    const int ct  = w & 1;               // agent tile this wave owns (B-operand / outputs)
    const int mt0 = w >> 1, mt1 = (w >> 1) + 2;   // feature tiles (A-operand)
    const int agent = 16 * ct + lr;
    const char* wsl = ws + (size_t)l * 16;

    // ---- stage X (contiguous 8800 f32) + adj ----
    {
        const float4* Xg = (const float4*)(X + (size_t)b * NN * DK);
        float4* sx = (float4*)(sm + SM_X);
        for (int i = tid; i < 2200; i += 256) sx[i] = Xg[i];
        ((float4*)(sm + SM_ADJ))[tid] = ((const float4*)(adj + (size_t)b * NN * NN))[tid];
    }
    __syncthreads();

    // ---- encoder: h1^T = W_enc^T (A) x X^T (B), bf16x3, relu ----
    {
        f4v acc0 = *(const f4v*)(b_enc + 16 * mt0 + 4 * lg);
        f4v acc1 = *(const f4v*)(b_enc + 16 * mt1 + 4 * lg);
        const float* sx = (const float*)(sm + SM_X);
#pragma unroll
        for (int s = 0; s < 9; ++s) {
            int kb = 32 * s + 8 * lg;
            s8v bh, bl;
#pragma unroll
            for (int e = 0; e < 8; ++e) {
                int k = kb + e;
                float x = (k < DK) ? sx[agent * DK + k] : 0.f;
                u16 hi = bf_hi(x);
                bh[e] = (short)hi;
                bl[e] = (short)bf_hi(x - bf_f(hi));
            }
            s8v a0h = *(const s8v*)(wsl + ((0*4 + mt0)*9 + s) * 1024);
            s8v a0l = *(const s8v*)(wsl + ((1*4 + mt0)*9 + s) * 1024);
            s8v a1h = *(const s8v*)(wsl + ((0*4 + mt1)*9 + s) * 1024);
            s8v a1l = *(const s8v*)(wsl + ((1*4 + mt1)*9 + s) * 1024);
            acc0 = MFMA(a0h, bh, acc0); acc0 = MFMA(a0h, bl, acc0); acc0 = MFMA(a0l, bh, acc0);
            acc1 = MFMA(a1h, bh, acc1); acc1 = MFMA(a1h, bl, acc1); acc1 = MFMA(a1l, bh, acc1);
        }
        write_hl4(sm + SM_HHI + agent*144 + (16*mt0 + 4*lg)*2,
                  sm + SM_HLO + agent*144 + (16*mt0 + 4*lg)*2, relu4(acc0));
        write_hl4(sm + SM_HHI + agent*144 + (16*mt1 + 4*lg)*2,
                  sm + SM_HLO + agent*144 + (16*mt1 + 4*lg)*2, relu4(acc1));
    }
    __syncthreads();

#pragma unroll
    for (int layer = 0; layer < 2; ++layer) {
        const float* bv = layer ? bv2 : bv1;
        const float* bk = layer ? bk2 : bk1;
        const float* bq = layer ? bq2 : bq1;
        const size_t lbase = WSE_SZ + (size_t)layer * 3 * WSL_SZ;

        // ---- QKV: {V,K,Q}^T = W^T x h^T, relu; Q/K -> row planes, V -> transposed plane ----
        {
            f4v acc[3][2];
            acc[0][0] = *(const f4v*)(bv + 16*mt0 + 4*lg); acc[0][1] = *(const f4v*)(bv + 16*mt1 + 4*lg);
            acc[1][0] = *(const f4v*)(bk + 16*mt0 + 4*lg); acc[1][1] = *(const f4v*)(bk + 16*mt1 + 4*lg);
            acc[2][0] = *(const f4v*)(bq + 16*mt0 + 4*lg); acc[2][1] = *(const f4v*)(bq + 16*mt1 + 4*lg);
            const char* hH = sm + SM_HHI + agent * 144;
            const char* hL = sm + SM_HLO + agent * 144;
#pragma unroll
            for (int s = 0; s < 2; ++s) {
                s8v bh = *(const s8v*)(hH + 64*s + 16*lg);
                s8v bl = *(const s8v*)(hL + 64*s + 16*lg);
#pragma unroll
                for (int m = 0; m < 3; ++m) {
                    const char* wb = wsl + lbase + (size_t)m * WSL_SZ;
                    s8v a0h = *(const s8v*)(wb + ((0*4 + mt0)*2 + s) * 1024);
                    s8v a0l = *(const s8v*)(wb + ((1*4 + mt0)*2 + s) * 1024);
                    s8v a1h = *(const s8v*)(wb + ((0*4 + mt1)*2 + s) * 1024);
                    s8v a1l = *(const s8v*)(wb + ((1*4 + mt1)*2 + s) * 1024);
                    acc[m][0] = MFMA(a0h, bh, acc[m][0]); acc[m][0] = MFMA(a0h, bl, acc[m][0]); acc[m][0] = MFMA(a0l, bh, acc[m][0]);
                    acc[m][1] = MFMA(a1h, bh, acc[m][1]); acc[m][1] = MFMA(a1h, bl, acc[m][1]); acc[m][1] = MFMA(a1l, bh, acc[m][1]);
                }
            }
#pragma unroll
            for (int t = 0; t < 2; ++t) {
                int mt = t ? mt1 : mt0;
                f4v vv = relu4(acc[0][t]);                  // V -> Vt[feat][agent]
#pragma unroll
                for (int r = 0; r < 4; ++r) {
                    int feat = 16*mt + 4*lg + r;
                    u16 hi = bf_hi(vv[r]);
                    *(u16*)(sm + SM_VTHI + feat*80 + agent*2) = hi;
                    *(u16*)(sm + SM_VTLO + feat*80 + agent*2) = bf_hi(vv[r] - bf_f(hi));
                }
                write_hl4(sm + SM_KHI + agent*144 + (16*mt + 4*lg)*2,
                          sm + SM_KLO + agent*144 + (16*mt + 4*lg)*2, relu4(acc[1][t]));
                write_hl4(sm + SM_QHI + agent*144 + (16*mt + 4*lg)*2,
                          sm + SM_QLO + agent*144 + (16*mt + 4*lg)*2, relu4(acc[2][t]));
            }
        }
        __syncthreads();

        // ---- scores = Q x K^T (bf16x3), one 16x16 tile per wave ----
        {
            const int mtq = w & 1, ctk = w >> 1;
            f4v acc = {0.f, 0.f, 0.f, 0.f};
            const char* qH = sm + SM_QHI + (16*mtq + lr) * 144;
            const char* qL = sm + SM_QLO + (16*mtq + lr) * 144;
            const char* kH = sm + SM_KHI + (16*ctk + lr) * 144;
            const char* kL = sm + SM_KLO + (16*ctk + lr) * 144;
#pragma unroll
            for (int s = 0; s < 2; ++s) {
                s8v ah = *(const s8v*)(qH + 64*s + 16*lg);
                s8v al = *(const s8v*)(qL + 64*s + 16*lg);
                s8v bh = *(const s8v*)(kH + 64*s + 16*lg);
                s8v bl = *(const s8v*)(kL + 64*s + 16*lg);
                acc = MFMA(ah, bh, acc); acc = MFMA(ah, bl, acc); acc = MFMA(al, bh, acc);
            }
            float* ss = (float*)(sm + SM_SS);
#pragma unroll
            for (int r = 0; r < 4; ++r)
                ss[(16*mtq + 4*lg + r) * 33 + 16*ctk + lr] = acc[r];
        }
        __syncthreads();

        // ---- masked softmax (fp32, wave-parallel 32-lane segments) -> P hi/lo planes ----
        {
            const int m = tid & 31, ng = tid >> 5;
            const float* ss = (const float*)(sm + SM_SS);
            const float* ad = (const float*)(sm + SM_ADJ);
#pragma unroll
            for (int i = 0; i < 4; ++i) {
                int n = ng * 4 + i;
                float mk = ad[n * 32 + m];
                float v  = ss[n * 33 + m] * mk - 9e15f * (1.f - mk);
                float mx = v;
#pragma unroll
                for (int off = 16; off; off >>= 1) mx = fmaxf(mx, __shfl_xor(mx, off, 32));
                float e = __expf(v - mx);
                float s = e;
#pragma unroll
                for (int off = 16; off; off >>= 1) s += __shfl_xor(s, off, 32);
                float p = e / s;
                u16 hi = bf_hi(p);
                *(u16*)(sm + SM_PHI + n*80 + m*2) = hi;
                *(u16*)(sm + SM_PLO + n*80 + m*2) = bf_hi(p - bf_f(hi));
            }
        }
        __syncthreads();

        // ---- PV: h^T = V^T (A, from Vt planes) x P^T (B, from P planes), K=32 ----
        {
            f4v acc0 = {0.f,0.f,0.f,0.f}, acc1 = {0.f,0.f,0.f,0.f};
            s8v bh  = *(const s8v*)(sm + SM_PHI + (16*ct + lr)*80 + 16*lg);
            s8v bl  = *(const s8v*)(sm + SM_PLO + (16*ct + lr)*80 + 16*lg);
            s8v a0h = *(const s8v*)(sm + SM_VTHI + (16*mt0 + lr)*80 + 16*lg);
            s8v a0l = *(const s8v*)(sm + SM_VTLO + (16*mt0 + lr)*80 + 16*lg);
            s8v a1h = *(const s8v*)(sm + SM_VTHI + (16*mt1 + lr)*80 + 16*lg);
            s8v a1l = *(const s8v*)(sm + SM_VTLO + (16*mt1 + lr)*80 + 16*lg);
            acc0 = MFMA(a0h, bh, acc0); acc0 = MFMA(a0h, bl, acc0); acc0 = MFMA(a0l, bh, acc0);
            acc1 = MFMA(a1h, bh, acc1); acc1 = MFMA(a1h, bl, acc1); acc1 = MFMA(a1l, bh, acc1);
            // overwrite h planes (no relu on attention output)
            write_hl4(sm + SM_HHI + agent*144 + (16*mt0 + 4*lg)*2,
                      sm + SM_HLO + agent*144 + (16*mt0 + 4*lg)*2, acc0);
            write_hl4(sm + SM_HHI + agent*144 + (16*mt1 + 4*lg)*2,
                      sm + SM_HLO + agent*144 + (16*mt1 + 4*lg)*2, acc1);
        }
        __syncthreads();
    }

    // ---- head: q^T = Wqn^T x h3^T (waves 0,1 only; a-dim padded 14->16) ----
    if (w < 2) {
        const int ag = 16 * w + lr;
        f4v acc;
#pragma unroll
        for (int r = 0; r < 4; ++r) { int a = 4*lg + r; acc[r] = (a < AA) ? bqn[a] : 0.f; }
        const char* hH = sm + SM_HHI + ag * 144;
        const char* hL = sm + SM_HLO + ag * 144;
#pragma unroll
        for (int s = 0; s < 2; ++s) {
            s8v bh = *(const s8v*)(hH + 64*s + 16*lg);
            s8v bl = *(const s8v*)(hL + 64*s + 16*lg);
            s8v ah = *(const s8v*)(wsl + WSQN_OFF + (0*2 + s) * 1024);
            s8v al = *(const s8v*)(wsl + WSQN_OFF + (1*2 + s) * 1024);
            acc = MFMA(ah, bh, acc); acc = MFMA(ah, bl, acc); acc = MFMA(al, bh, acc);
        }
        float* op = Out + ((size_t)b * NN + ag) * AA;
#pragma unroll
        for (int r = 0; r < 4; ++r) { int a = 4*lg + r; if (a < AA) op[a] = acc[r]; }
    }
}

__global__ void copy_hidden(const float4* __restrict__ src,
                            float4* __restrict__ dst, int n4)
{
    int i = blockIdx.x * blockDim.x + threadIdx.x;
    int stride = gridDim.x * blockDim.x;
    for (; i < n4; i += stride) dst[i] = src[i];
}

extern "C" void kernel_launch(void* const* d_in, const int* in_sizes, int n_in,
                              void* d_out, int out_size, void* d_ws, size_t ws_size,
                              hipStream_t stream)
{
    const float* X    = (const float*)d_in[0];
    const float* hid  = (const float*)d_in[1];
    const float* adj  = (const float*)d_in[2];
    const float* W_enc = (const float*)d_in[3];
    const float* b_enc = (const float*)d_in[4];
    const float* Wv1 = (const float*)d_in[5];  const float* bv1 = (const float*)d_in[6];
    const float* Wk1 = (const float*)d_in[7];  const float* bk1 = (const float*)d_in[8];
    const float* Wq1 = (const float*)d_in[9];  const float* bq1 = (const float*)d_in[10];
    const float* Wv2 = (const float*)d_in[11]; const float* bv2 = (const float*)d_in[12];
    const float* Wk2 = (const float*)d_in[13]; const float* bk2 = (const float*)d_in[14];
    const float* Wq2 = (const float*)d_in[15]; const float* bq2 = (const float*)d_in[16];
    const float* Wqn = (const float*)d_in[17]; const float* bqn = (const float*)d_in[18];
    float* out = (float*)d_out;
    char* ws = (char*)d_ws;   // needs 176,128 B

    prepack_w<<<43, 256, 0, stream>>>(W_enc, Wv1, Wk1, Wq1, Wv2, Wk2, Wq2, Wqn, ws);

    dgn_mfma<<<NB, 256, 0, stream>>>(X, adj, ws, b_enc,
                                     bv1, bk1, bq1, bv2, bk2, bq2, bqn, out);

    copy_hidden<<<2048, 256, 0, stream>>>((const float4*)hid,
                                          (float4*)(out + Q_ELEMS),
                                          (int)(HID_ELEMS / 4));
}

// Round 3
// 398.690 us; speedup vs baseline: 3.3322x; 1.3060x over previous
//
#include <hip/hip_runtime.h>

// ---------------- problem constants ----------------
#define NB 16384
#define NN 32
#define DK 275
#define HH 64
#define AA 14
#define Q_ELEMS   ((size_t)NB * NN * AA)
#define HID_ELEMS ((size_t)NB * NN * HH)

typedef unsigned short u16;
typedef unsigned int   u32;
typedef __attribute__((ext_vector_type(8))) short s8v;   // 8 bf16 (4 VGPR)
typedef __attribute__((ext_vector_type(4))) float f4v;   // MFMA acc

#define MFMA(a,b,c) __builtin_amdgcn_mfma_f32_16x16x32_bf16((a),(b),(c),0,0,0)

__device__ __forceinline__ u16 bf_hi(float x){
    union{float f; u32 u;} v; v.f = x;
    u32 r = v.u + 0x7fffu + ((v.u >> 16) & 1u);
    return (u16)(r >> 16);
}
__device__ __forceinline__ float bf_f(u16 h){
    union{u32 u; float f;} v; v.u = ((u32)h) << 16; return v.f;
}

// ---------------- ws (prepacked weight fragments), same as R2 ----------------
#define WSE_OFF 0
#define WSE_SZ  (2*4*9*1024)
#define WSL_SZ  (2*4*2*1024)
#define WSQN_OFF (WSE_SZ + 6*WSL_SZ)

__global__ void prepack_w(const float* __restrict__ We,
                          const float* __restrict__ Wv1, const float* __restrict__ Wk1, const float* __restrict__ Wq1,
                          const float* __restrict__ Wv2, const float* __restrict__ Wk2, const float* __restrict__ Wq2,
                          const float* __restrict__ Wqn, char* __restrict__ ws)
{
    int gid  = blockIdx.x * 256 + threadIdx.x;
    int slot = gid >> 6, lane = gid & 63;
    const float* W; int K, OUT, STEPS, MT; size_t base; int rem;
    if (slot < 72) { W = We; K = DK; OUT = 64; STEPS = 9; MT = 4; base = WSE_OFF; rem = slot; }
    else if (slot < 168) {
        int q = slot - 72; int mat = q >> 4; rem = q & 15;
        W = mat==0?Wv1 : mat==1?Wk1 : mat==2?Wq1 : mat==3?Wv2 : mat==4?Wk2 : Wq2;
        K = 64; OUT = 64; STEPS = 2; MT = 4; base = WSE_SZ + (size_t)mat * WSL_SZ;
    } else { W = Wqn; K = 64; OUT = AA; STEPS = 2; MT = 1; base = WSQN_OFF; rem = slot - 168; }
    int o  = 16 * (((rem / STEPS) % MT)) + (lane & 15);
    int part = (rem / STEPS) / MT;
    int s  = rem % STEPS;
    int kb = 32 * s + 8 * (lane >> 4);
    u16 h[8];
#pragma unroll
    for (int e = 0; e < 8; ++e) {
        int k = kb + e;
        float x = (k < K && o < OUT) ? W[(size_t)k * OUT + o] : 0.f;
        u16 hi = bf_hi(x);
        h[e] = (part == 0) ? hi : bf_hi(x - bf_f(hi));
    }
    uint4 d;
    d.x = (u32)h[0] | ((u32)h[1] << 16);
    d.y = (u32)h[2] | ((u32)h[3] << 16);
    d.z = (u32)h[4] | ((u32)h[5] << 16);
    d.w = (u32)h[6] | ((u32)h[7] << 16);
    *(uint4*)(ws + base + (size_t)rem * 1024 + (size_t)lane * 16) = d;
}

// ---------------- LDS layout (bytes) ----------------
// Overlay region [0, 26112):
//   staging phase A: XAHI 32x336, XALO 32x336 (k 0..159)
//   staging phase B: XBHI 32x272, XBLO 32x272 (k 160..287, zero-padded >=275)
//   after encoder:   QHI/QLO/KHI/KLO 32x144 each, VT 64x80 (single bf16), P 32x80 (single)
#define SM_XAHI 0
#define SM_XALO 10752
#define SM_XBHI 0
#define SM_XBLO 8704
#define SM_QHI  0
#define SM_QLO  4608
#define SM_KHI  9216
#define SM_KLO  13824
#define SM_VT   18432
#define SM_P    23552
#define SM_HHI  26112
#define SM_HLO  30720
#define SM_ADJ  35328
#define SM_TOT  39424

__device__ __forceinline__ f4v relu4(f4v v){
    f4v r; r[0]=fmaxf(v[0],0.f); r[1]=fmaxf(v[1],0.f);
    r[2]=fmaxf(v[2],0.f); r[3]=fmaxf(v[3],0.f); return r;
}
__device__ __forceinline__ void write_hl4(char* hp, char* lp, f4v v){
    u16 h0=bf_hi(v[0]), h1=bf_hi(v[1]), h2=bf_hi(v[2]), h3=bf_hi(v[3]);
    uint2 hw; hw.x = (u32)h0 | ((u32)h1<<16); hw.y = (u32)h2 | ((u32)h3<<16);
    u16 l0=bf_hi(v[0]-bf_f(h0)), l1=bf_hi(v[1]-bf_f(h1));
    u16 l2=bf_hi(v[2]-bf_f(h2)), l3=bf_hi(v[3]-bf_f(h3));
    uint2 lw; lw.x = (u32)l0 | ((u32)l1<<16); lw.y = (u32)l2 | ((u32)l3<<16);
    *(uint2*)hp = hw; *(uint2*)lp = lw;
}
__device__ __forceinline__ void stage4(char* hrow, char* lrow, int k0,
                                       float x0, float x1, float x2, float x3){
    u16 h0=bf_hi(x0), h1=bf_hi(x1), h2=bf_hi(x2), h3=bf_hi(x3);
    uint2 hw; hw.x=(u32)h0|((u32)h1<<16); hw.y=(u32)h2|((u32)h3<<16);
    u16 l0=bf_hi(x0-bf_f(h0)), l1=bf_hi(x1-bf_f(h1));
    u16 l2=bf_hi(x2-bf_f(h2)), l3=bf_hi(x3-bf_f(h3));
    uint2 lw; lw.x=(u32)l0|((u32)l1<<16); lw.y=(u32)l2|((u32)l3<<16);
    *(uint2*)(hrow + 2*k0) = hw; *(uint2*)(lrow + 2*k0) = lw;
}

__global__ __launch_bounds__(256, 4) void dgn_mfma(
    const float* __restrict__ X, const float* __restrict__ adj,
    const char*  __restrict__ ws,
    const float* __restrict__ b_enc,
    const float* __restrict__ bv1, const float* __restrict__ bk1, const float* __restrict__ bq1,
    const float* __restrict__ bv2, const float* __restrict__ bk2, const float* __restrict__ bq2,
    const float* __restrict__ bqn,
    float* __restrict__ Out)
{
    __shared__ __align__(16) char sm[SM_TOT];
    const int b = blockIdx.x, tid = threadIdx.x;
    const int w = tid >> 6, l = tid & 63, lr = l & 15, lg = l >> 4;
    const int ct  = w & 1;
    const int mt0 = w >> 1, mt1 = (w >> 1) + 2;
    const int agent = 16 * ct + lr;
    const char* wsl = ws + (size_t)l * 16;
    const int t8 = tid & 7, ag8 = tid >> 3;          // staging: 8 threads/agent
    const float* xrow = X + (size_t)b * NN * DK + (size_t)ag8 * DK;

    // ---- stage X phase A (k 0..159) as bf16 hi/lo + adj ----
    {
        char* hrow = sm + SM_XAHI + ag8 * 336;
        char* lrow = sm + SM_XALO + ag8 * 336;
#pragma unroll
        for (int it = 0; it < 5; ++it) {
            int k0 = 4 * t8 + 32 * it;               // 0..156
            stage4(hrow, lrow, k0, xrow[k0], xrow[k0+1], xrow[k0+2], xrow[k0+3]);
        }
        ((float4*)(sm + SM_ADJ))[tid] = ((const float4*)(adj + (size_t)b * NN * NN))[tid];
    }
    __syncthreads();

    // ---- encoder phase A: s = 0..4 (split accumulator chains: hh + cross) ----
    f4v ehh0 = *(const f4v*)(b_enc + 16*mt0 + 4*lg);
    f4v ehh1 = *(const f4v*)(b_enc + 16*mt1 + 4*lg);
    f4v ecx0 = {0.f,0.f,0.f,0.f}, ecx1 = {0.f,0.f,0.f,0.f};
    {
        const char* xh = sm + SM_XAHI + agent*336 + 16*lg;
        const char* xl = sm + SM_XALO + agent*336 + 16*lg;
#pragma unroll
        for (int s = 0; s < 5; ++s) {
            s8v bh = *(const s8v*)(xh + 64*s);
            s8v bl = *(const s8v*)(xl + 64*s);
            s8v a0h = *(const s8v*)(wsl + ((0*4 + mt0)*9 + s) * 1024);
            s8v a0l = *(const s8v*)(wsl + ((1*4 + mt0)*9 + s) * 1024);
            s8v a1h = *(const s8v*)(wsl + ((0*4 + mt1)*9 + s) * 1024);
            s8v a1l = *(const s8v*)(wsl + ((1*4 + mt1)*9 + s) * 1024);
            ehh0 = MFMA(a0h, bh, ehh0); ecx0 = MFMA(a0h, bl, ecx0); ecx0 = MFMA(a0l, bh, ecx0);
            ehh1 = MFMA(a1h, bh, ehh1); ecx1 = MFMA(a1h, bl, ecx1); ecx1 = MFMA(a1l, bh, ecx1);
        }
    }
    __syncthreads();

    // ---- stage X phase B (k 160..287, zero pad >= 275) ----
    {
        char* hrow = sm + SM_XBHI + ag8 * 272;
        char* lrow = sm + SM_XBLO + ag8 * 272;
#pragma unroll
        for (int it = 0; it < 4; ++it) {
            int k0 = 4 * t8 + 32 * it;               // local 0..124
            float x[4];
#pragma unroll
            for (int j2 = 0; j2 < 4; ++j2) {
                int k = 160 + k0 + j2;
                x[j2] = (k < DK) ? xrow[k] : 0.f;
            }
            stage4(hrow, lrow, k0, x[0], x[1], x[2], x[3]);
        }
    }
    __syncthreads();

    // ---- encoder phase B: s = 5..8; then h1 = relu ----
    {
        const char* xh = sm + SM_XBHI + agent*272 + 16*lg;
        const char* xl = sm + SM_XBLO + agent*272 + 16*lg;
#pragma unroll
        for (int s = 5; s < 9; ++s) {
            s8v bh = *(const s8v*)(xh + 64*(s-5));
            s8v bl = *(const s8v*)(xl + 64*(s-5));
            s8v a0h = *(const s8v*)(wsl + ((0*4 + mt0)*9 + s) * 1024);
            s8v a0l = *(const s8v*)(wsl + ((1*4 + mt0)*9 + s) * 1024);
            s8v a1h = *(const s8v*)(wsl + ((0*4 + mt1)*9 + s) * 1024);
            s8v a1l = *(const s8v*)(wsl + ((1*4 + mt1)*9 + s) * 1024);
            ehh0 = MFMA(a0h, bh, ehh0); ecx0 = MFMA(a0h, bl, ecx0); ecx0 = MFMA(a0l, bh, ecx0);
            ehh1 = MFMA(a1h, bh, ehh1); ecx1 = MFMA(a1h, bl, ecx1); ecx1 = MFMA(a1l, bh, ecx1);
        }
        write_hl4(sm + SM_HHI + agent*144 + (16*mt0 + 4*lg)*2,
                  sm + SM_HLO + agent*144 + (16*mt0 + 4*lg)*2, relu4(ehh0 + ecx0));
        write_hl4(sm + SM_HHI + agent*144 + (16*mt1 + 4*lg)*2,
                  sm + SM_HLO + agent*144 + (16*mt1 + 4*lg)*2, relu4(ehh1 + ecx1));
    }
    __syncthreads();

#pragma unroll
    for (int layer = 0; layer < 2; ++layer) {
        const float* bv = layer ? bv2 : bv1;
        const float* bk = layer ? bk2 : bk1;
        const float* bq = layer ? bq2 : bq1;
        const size_t lbase = WSE_SZ + (size_t)layer * 3 * WSL_SZ;

        // ---- QKV (split chains); V -> single-bf16 Vt, K/Q -> hi/lo planes ----
        {
            f4v hh[3][2], cx[3][2];
            hh[0][0] = *(const f4v*)(bv + 16*mt0 + 4*lg); hh[0][1] = *(const f4v*)(bv + 16*mt1 + 4*lg);
            hh[1][0] = *(const f4v*)(bk + 16*mt0 + 4*lg); hh[1][1] = *(const f4v*)(bk + 16*mt1 + 4*lg);
            hh[2][0] = *(const f4v*)(bq + 16*mt0 + 4*lg); hh[2][1] = *(const f4v*)(bq + 16*mt1 + 4*lg);
#pragma unroll
            for (int m = 0; m < 3; ++m) { cx[m][0] = f4v{0.f,0.f,0.f,0.f}; cx[m][1] = f4v{0.f,0.f,0.f,0.f}; }
            const char* hH = sm + SM_HHI + agent * 144 + 16*lg;
            const char* hL = sm + SM_HLO + agent * 144 + 16*lg;
#pragma unroll
            for (int s = 0; s < 2; ++s) {
                s8v bh = *(const s8v*)(hH + 64*s);
                s8v bl = *(const s8v*)(hL + 64*s);
#pragma unroll
                for (int m = 0; m < 3; ++m) {
                    const char* wb = wsl + lbase + (size_t)m * WSL_SZ;
                    s8v a0h = *(const s8v*)(wb + ((0*4 + mt0)*2 + s) * 1024);
                    s8v a0l = *(const s8v*)(wb + ((1*4 + mt0)*2 + s) * 1024);
                    s8v a1h = *(const s8v*)(wb + ((0*4 + mt1)*2 + s) * 1024);
                    s8v a1l = *(const s8v*)(wb + ((1*4 + mt1)*2 + s) * 1024);
                    hh[m][0] = MFMA(a0h, bh, hh[m][0]);
                    cx[m][0] = MFMA(a0h, bl, cx[m][0]); cx[m][0] = MFMA(a0l, bh, cx[m][0]);
                    hh[m][1] = MFMA(a1h, bh, hh[m][1]);
                    cx[m][1] = MFMA(a1h, bl, cx[m][1]); cx[m][1] = MFMA(a1l, bh, cx[m][1]);
                }
            }
#pragma unroll
            for (int t = 0; t < 2; ++t) {
                int mt = t ? mt1 : mt0;
                f4v vv = relu4(hh[0][t] + cx[0][t]);
#pragma unroll
                for (int r = 0; r < 4; ++r)
                    *(u16*)(sm + SM_VT + (16*mt + 4*lg + r)*80 + agent*2) = bf_hi(vv[r]);
                write_hl4(sm + SM_KHI + agent*144 + (16*mt + 4*lg)*2,
                          sm + SM_KLO + agent*144 + (16*mt + 4*lg)*2, relu4(hh[1][t] + cx[1][t]));
                write_hl4(sm + SM_QHI + agent*144 + (16*mt + 4*lg)*2,
                          sm + SM_QLO + agent*144 + (16*mt + 4*lg)*2, relu4(hh[2][t] + cx[2][t]));
            }
        }
        __syncthreads();

        // ---- fused scores + masked softmax (waves 0,1; wave w owns rows 16w..16w+15) ----
        if (w < 2) {
            f4v shh[2] = {{0.f,0.f,0.f,0.f},{0.f,0.f,0.f,0.f}};
            f4v scx[2] = {{0.f,0.f,0.f,0.f},{0.f,0.f,0.f,0.f}};
            const char* qH = sm + SM_QHI + (16*w + lr)*144 + 16*lg;
            const char* qL = sm + SM_QLO + (16*w + lr)*144 + 16*lg;
#pragma unroll
            for (int s = 0; s < 2; ++s) {
                s8v ah = *(const s8v*)(qH + 64*s);
                s8v al = *(const s8v*)(qL + 64*s);
#pragma unroll
                for (int t = 0; t < 2; ++t) {
                    s8v bh = *(const s8v*)(sm + SM_KHI + (16*t + lr)*144 + 16*lg + 64*s);
                    s8v bl = *(const s8v*)(sm + SM_KLO + (16*t + lr)*144 + 16*lg + 64*s);
                    shh[t] = MFMA(ah, bh, shh[t]);
                    scx[t] = MFMA(ah, bl, scx[t]); scx[t] = MFMA(al, bh, scx[t]);
                }
            }
            const float* ad = (const float*)(sm + SM_ADJ);
#pragma unroll
            for (int r = 0; r < 4; ++r) {
                int row = 16*w + 4*lg + r;
                float m0 = ad[row*32 + lr], m1 = ad[row*32 + 16 + lr];
                float v0 = (shh[0][r] + scx[0][r]) * m0 - 9e15f * (1.f - m0);
                float v1 = (shh[1][r] + scx[1][r]) * m1 - 9e15f * (1.f - m1);
                float mx = fmaxf(v0, v1);
#pragma unroll
                for (int off = 8; off; off >>= 1) mx = fmaxf(mx, __shfl_xor(mx, off, 16));
                float e0 = __expf(v0 - mx), e1 = __expf(v1 - mx);
                float ssum = e0 + e1;
#pragma unroll
                for (int off = 8; off; off >>= 1) ssum += __shfl_xor(ssum, off, 16);
                float inv = 1.f / ssum;
                *(u16*)(sm + SM_P + row*80 + lr*2)      = bf_hi(e0 * inv);
                *(u16*)(sm + SM_P + row*80 + (16+lr)*2) = bf_hi(e1 * inv);
            }
        }
        __syncthreads();

        // ---- PV: h^T = Vt x P^T (single bf16, K=32 -> 1 MFMA per tile) ----
        {
            s8v pb  = *(const s8v*)(sm + SM_P  + (16*ct  + lr)*80 + 16*lg);
            s8v va0 = *(const s8v*)(sm + SM_VT + (16*mt0 + lr)*80 + 16*lg);
            s8v va1 = *(const s8v*)(sm + SM_VT + (16*mt1 + lr)*80 + 16*lg);
            f4v h0 = {0.f,0.f,0.f,0.f}, h1 = {0.f,0.f,0.f,0.f};
            h0 = MFMA(va0, pb, h0);
            h1 = MFMA(va1, pb, h1);
            write_hl4(sm + SM_HHI + agent*144 + (16*mt0 + 4*lg)*2,
                      sm + SM_HLO + agent*144 + (16*mt0 + 4*lg)*2, h0);
            write_hl4(sm + SM_HHI + agent*144 + (16*mt1 + 4*lg)*2,
                      sm + SM_HLO + agent*144 + (16*mt1 + 4*lg)*2, h1);
        }
        __syncthreads();
    }

    // ---- head: q^T = Wqn^T x h3^T (waves 0,1; split chains) ----
    if (w < 2) {
        const int ag = 16 * w + lr;
        f4v hacc, cacc = {0.f,0.f,0.f,0.f};
#pragma unroll
        for (int r = 0; r < 4; ++r) { int a = 4*lg + r; hacc[r] = (a < AA) ? bqn[a] : 0.f; }
        const char* hH = sm + SM_HHI + ag * 144 + 16*lg;
        const char* hL = sm + SM_HLO + ag * 144 + 16*lg;
#pragma unroll
        for (int s = 0; s < 2; ++s) {
            s8v bh = *(const s8v*)(hH + 64*s);
            s8v bl = *(const s8v*)(hL + 64*s);
            s8v ah = *(const s8v*)(wsl + WSQN_OFF + (0*2 + s) * 1024);
            s8v al = *(const s8v*)(wsl + WSQN_OFF + (1*2 + s) * 1024);
            hacc = MFMA(ah, bh, hacc);
            cacc = MFMA(ah, bl, cacc); cacc = MFMA(al, bh, cacc);
        }
        f4v acc = hacc + cacc;
        float* op = Out + ((size_t)b * NN + ag) * AA;
#pragma unroll
        for (int r = 0; r < 4; ++r) { int a = 4*lg + r; if (a < AA) op[a] = acc[r]; }
    }
}

__global__ void copy_hidden(const float4* __restrict__ src,
                            float4* __restrict__ dst, int n4)
{
    int i = blockIdx.x * blockDim.x + threadIdx.x;
    int stride = gridDim.x * blockDim.x;
    for (; i < n4; i += stride) dst[i] = src[i];
}

extern "C" void kernel_launch(void* const* d_in, const int* in_sizes, int n_in,
                              void* d_out, int out_size, void* d_ws, size_t ws_size,
                              hipStream_t stream)
{
    const float* X    = (const float*)d_in[0];
    const float* hid  = (const float*)d_in[1];
    const float* adj  = (const float*)d_in[2];
    const float* W_enc = (const float*)d_in[3];
    const float* b_enc = (const float*)d_in[4];
    const float* Wv1 = (const float*)d_in[5];  const float* bv1 = (const float*)d_in[6];
    const float* Wk1 = (const float*)d_in[7];  const float* bk1 = (const float*)d_in[8];
    const float* Wq1 = (const float*)d_in[9];  const float* bq1 = (const float*)d_in[10];
    const float* Wv2 = (const float*)d_in[11]; const float* bv2 = (const float*)d_in[12];
    const float* Wk2 = (const float*)d_in[13]; const float* bk2 = (const float*)d_in[14];
    const float* Wq2 = (const float*)d_in[15]; const float* bq2 = (const float*)d_in[16];
    const float* Wqn = (const float*)d_in[17]; const float* bqn = (const float*)d_in[18];
    float* out = (float*)d_out;
    char* ws = (char*)d_ws;   // needs 176,128 B

    prepack_w<<<43, 256, 0, stream>>>(W_enc, Wv1, Wk1, Wq1, Wv2, Wk2, Wq2, Wqn, ws);

    dgn_mfma<<<NB, 256, 0, stream>>>(X, adj, ws, b_enc,
                                     bv1, bk1, bq1, bv2, bk2, bq2, bqn, out);

    copy_hidden<<<2048, 256, 0, stream>>>((const float4*)hid,
                                          (float4*)(out + Q_ELEMS),
                                          (int)(HID_ELEMS / 4));
}